// Round 3
// baseline (502.736 us; speedup 1.0000x reference)
//
#include <hip/hip_runtime.h>
#include <math.h>

// Problem constants
#define BB 4
#define CC 64
#define HH 128
#define WW 128
#define GG 8
#define COO 64
#define HWC (HH*WW)

// Deform LDS layout: pixel stride 12 u32 (48 B, 16B aligned), row padded to 26
#define DPAD 12
#define DROW 26

typedef float f32x4 __attribute__((ext_vector_type(4)));
typedef __bf16 bf16x8 __attribute__((ext_vector_type(8)));

__device__ __forceinline__ unsigned short bf16_rn(float f) {
    unsigned int u = __float_as_uint(f);
    unsigned int r = (u + 0x7fffu + ((u >> 16) & 1u)) >> 16;
    return (unsigned short)r;
}
__device__ __forceinline__ float b2f(unsigned short u) {
    return __uint_as_float(((unsigned int)u) << 16);
}

// ---------------------------------------------------------------------------
// Fused input pack: one launch produces
//   xs   : NCHW u32 {lo=bf16(x), hi=bf16(share)}   (deform source)
//   sc16 : share in c16 layout [((b*4+cg)*HWC+pix)*16+ci]  (conv B)
//   oc16 : offset_feat in c16 layout                       (conv B)
// ---------------------------------------------------------------------------
__global__ __launch_bounds__(256) void pack_inputs_kernel(
    const float* __restrict__ x, const float* __restrict__ share,
    const float* __restrict__ offf,
    unsigned int* __restrict__ xs, unsigned short* __restrict__ sc16,
    unsigned short* __restrict__ oc16)
{
    __shared__ unsigned short lds[64][66];
    const int b = blockIdx.y;
    const int pix0 = blockIdx.x * 64;
    const int t = threadIdx.x;
    const int p = t & 63, q = t >> 6;
    const int pl = t & 63, cg = t >> 6;

    // Phase 1: share -> lds + xs write (share & x elementwise)
#pragma unroll
    for (int i = 0; i < 16; i++) {
        int c = i * 4 + q;
        size_t idx = ((size_t)b * 64 + c) * HWC + pix0 + p;
        unsigned short sb = bf16_rn(share[idx]);
        lds[c][p] = sb;
        xs[idx] = (unsigned int)bf16_rn(x[idx]) | ((unsigned int)sb << 16);
    }
    __syncthreads();
    {
        unsigned int u[8];
#pragma unroll
        for (int j = 0; j < 8; j++) {
            unsigned int lo = lds[cg * 16 + 2 * j][pl];
            unsigned int hi = lds[cg * 16 + 2 * j + 1][pl];
            u[j] = lo | (hi << 16);
        }
        unsigned int* dst = (unsigned int*)(sc16 + ((size_t)(b * 4 + cg) * HWC + pix0 + pl) * 16);
        *(uint4*)dst = make_uint4(u[0], u[1], u[2], u[3]);
        *(uint4*)(dst + 4) = make_uint4(u[4], u[5], u[6], u[7]);
    }
    __syncthreads();

    // Phase 2: offset_feat -> lds -> oc16
#pragma unroll
    for (int i = 0; i < 16; i++) {
        int c = i * 4 + q;
        lds[c][p] = bf16_rn(offf[((size_t)b * 64 + c) * HWC + pix0 + p]);
    }
    __syncthreads();
    {
        unsigned int u[8];
#pragma unroll
        for (int j = 0; j < 8; j++) {
            unsigned int lo = lds[cg * 16 + 2 * j][pl];
            unsigned int hi = lds[cg * 16 + 2 * j + 1][pl];
            u[j] = lo | (hi << 16);
        }
        unsigned int* dst = (unsigned int*)(oc16 + ((size_t)(b * 4 + cg) * HWC + pix0 + pl) * 16);
        *(uint4*)dst = make_uint4(u[0], u[1], u[2], u[3]);
        *(uint4*)(dst + 4) = make_uint4(u[4], u[5], u[6], u[7]);
    }
}

// ---------------------------------------------------------------------------
// Weight packs for 16x16x32 MFMA fragments.
// Layout: wp[(t*(COP/16)+cob)*64 + lane][8] bf16, where t = seg*18 + kk*2 + ks,
// lane holds co = cob*16+(lane&15), k_local = (lane>>4)*8 + j (j=0..7),
// cg = 2*ks + (k_local>>4), ci = k_local&15, cin = seg*64 + cg*16 + ci.
// Sizes (same as before): om 18*256*32=147456, em1 36*64*32=73728,
// em2 18*128*32=73728.
// ---------------------------------------------------------------------------
__device__ __forceinline__ void pack_w_one(const float* __restrict__ w,
                                           unsigned short* __restrict__ wp,
                                           int Cout, int COP, int CinTot, int idx) {
    int j    = idx & 7;
    int lane = (idx >> 3) & 63;
    int rem  = idx >> 9;              // t*(COP/16) + cob
    int ncob = COP >> 4;
    int cob  = rem % ncob;
    int t    = rem / ncob;
    int seg  = t / 18;
    int tt   = t % 18;
    int kk   = tt >> 1;
    int ks   = tt & 1;
    int co   = cob * 16 + (lane & 15);
    int kl   = ((lane >> 4) << 3) + j;     // 0..31
    int cg   = ks * 2 + (kl >> 4);
    int ci   = kl & 15;
    int cin  = seg * 64 + cg * 16 + ci;
    float v = (co < Cout) ? w[((size_t)co * CinTot + cin) * 9 + kk] : 0.f;
    wp[idx] = bf16_rn(v);
}

__global__ void pack_w_all_kernel(const float* __restrict__ w_om, unsigned short* __restrict__ wp_om,
                                  const float* __restrict__ w_em1, unsigned short* __restrict__ wp_em1,
                                  const float* __restrict__ w_em2, unsigned short* __restrict__ wp_em2) {
    int i = blockIdx.x * 256 + threadIdx.x;
    if (i < 147456) {
        pack_w_one(w_om, wp_om, 216, 256, 64, i);
    } else if (i < 147456 + 73728) {
        pack_w_one(w_em1, wp_em1, 64, 64, 128, i - 147456);
    } else if (i < 147456 + 73728 + 73728) {
        pack_w_one(w_em2, wp_em2, 72, 128, 64, i - 147456 - 73728);
    }
}

// ---------------------------------------------------------------------------
// Implicit-GEMM 3x3 conv via mfma_f32_16x16x32_bf16, inputs in c16 layout.
//
// R9: m97-shaped instruction mix. R8 post-mortem: compiler collapsed the
// rotating-buffer pipeline (VGPR stayed 88), each 32x32 step was
// 4 MFMA : 4 loads fully latency-exposed -> 10% MfmaUtil.
// Fix: 16x16x32 MFMA, wave tile 64co x 64px. Per K=32 step:
//   4 coalesced weight loads (L1-hot, shared by all 4 waves)
// + 4 ds_read_b128 (compile-time offsets into the staged tile)
// + 16 MFMA
// = the exact 16:8:2-class mix m97 sustains at 37% MfmaUtil without any
// source-level pipelining (compiler emits fine-grained lgkmcnt there).
// A 16x16x32 fragment's 4 lane-groups map to {cg pair, ci half}, so the
// K=32 fragment reads straight from the existing [cg][row][px][16ci] tile.
// ---------------------------------------------------------------------------
template<int NSEG, int COP>
__global__ __launch_bounds__(256) void conv_mfma_kernel(
    const unsigned short* __restrict__ in0,
    const unsigned short* __restrict__ in1,
    const unsigned short* __restrict__ wp,
    const float* __restrict__ bias,
    void* __restrict__ out,
    int Cout, int out_mode, int act)
{
    constexpr int PXW = 66;            // 64 px + 1 halo each side
    constexpr int NE  = 4 * 6 * PXW;   // 1584 entries of 32 B (16 bf16 ch)
    __shared__ __align__(16) unsigned short slds[NE * 16];   // 50688 B

    const int lane = threadIdx.x & 63;
    const int wid  = threadIdx.x >> 6;
    int tmp = blockIdx.x;
    const int xsp = tmp & 1; tmp >>= 1;    // XS = 2
    const int rb  = tmp & 31;              // HH/4 = 32
    const int b   = tmp >> 5;
    const int r0  = rb * 4;
    const int r   = r0 + wid;              // output row, wave-uniform
    const int px0 = xsp * 64;
    const int cb0 = blockIdx.y * 4;        // co block-of-16 base
    const int co0 = blockIdx.y * 64;

    f32x4 acc[4][4];
#pragma unroll
    for (int cob = 0; cob < 4; cob++)
#pragma unroll
        for (int nt = 0; nt < 4; nt++)
#pragma unroll
            for (int rg = 0; rg < 4; rg++) acc[cob][nt][rg] = 0.f;

    // B-fragment lane mapping for 16x16x32: col(px)=lane&15, k=(lane>>4)*8+j.
    // k 0..31 -> lane groups {cg0 ci0-7, cg0 ci8-15, cg1 ci0-7, cg1 ci8-15}.
    const int pxl  = lane & 15;
    const int kgrp = lane >> 4;            // 0..3
    const int cglh = lane >> 5;            // cg within pair
    const int cil0 = (kgrp & 1) * 8;       // ci half
    const unsigned short* lp = slds +
        ((size_t)(cglh * 6 + wid) * PXW + 1 + pxl) * 16 + cil0;

#pragma unroll
    for (int seg = 0; seg < NSEG; seg++) {
        const unsigned short* inb = (seg ? in1 : in0) + (size_t)b * 4 * HWC * 16;
        if (seg) __syncthreads();

        // ---- Stage 4 cg x 6 rows x 66 px, zero-padded (conv zero-padding) ----
#pragma unroll
        for (int i = 0; i < 7; i++) {
            const int e = (int)threadIdx.x + i * 256;
            if (i < 6 || e < NE) {
                const int cg  = e / (6 * PXW);
                const int rem = e - cg * (6 * PXW);
                const int row = rem / PXW;
                const int px  = rem - row * PXW;
                const int iy = r0 - 1 + row;
                const int ix = px0 - 1 + px;
                const bool valid = ((unsigned)iy < (unsigned)HH) && ((unsigned)ix < (unsigned)WW);
                const int iyc = min(max(iy, 0), HH - 1);
                const int ixc = min(max(ix, 0), WW - 1);
                const uint4* src = (const uint4*)(inb + ((size_t)cg * HWC + (size_t)iyc * WW + ixc) * 16);
                uint4 v0, v1;
                if (valid) { v0 = src[0]; v1 = src[1]; }
                else       { v0 = make_uint4(0u, 0u, 0u, 0u); v1 = v0; }
                uint4* dst = (uint4*)(slds + (size_t)e * 16);
                dst[0] = v0; dst[1] = v1;
            }
        }
        __syncthreads();

        // ---- Straight-line K loop: 18 steps of K=32, all offsets immediate ----
#pragma unroll
        for (int kk = 0; kk < 9; kk++) {
            const int kh = kk / 3, kw = kk % 3;
#pragma unroll
            for (int ks = 0; ks < 2; ks++) {
                const int t = seg * 18 + kk * 2 + ks;
                bf16x8 af[4];
#pragma unroll
                for (int cob = 0; cob < 4; cob++)
                    af[cob] = *(const bf16x8*)(wp +
                        ((size_t)(t * (COP >> 4) + cb0 + cob) * 64 + lane) * 8);
                bf16x8 bf[4];
#pragma unroll
                for (int nt = 0; nt < 4; nt++)
                    bf[nt] = *(const bf16x8*)(lp +
                        ((ks * 12 + kh) * PXW + nt * 16 + kw - 1) * 16);
#pragma unroll
                for (int cob = 0; cob < 4; cob++)
#pragma unroll
                    for (int nt = 0; nt < 4; nt++)
                        acc[cob][nt] = __builtin_amdgcn_mfma_f32_16x16x32_bf16(
                            af[cob], bf[nt], acc[cob][nt], 0, 0, 0);
            }
        }
    }

    // Epilogue: 16x16 D layout col(px)=lane&15, row(co)=(lane>>4)*4+rg
#pragma unroll
    for (int cob = 0; cob < 4; cob++) {
#pragma unroll
        for (int nt = 0; nt < 4; nt++) {
#pragma unroll
            for (int rg = 0; rg < 4; rg++) {
                const int co = co0 + cob * 16 + kgrp * 4 + rg;
                if (co < Cout) {
                    float v = acc[cob][nt][rg] + bias[co];
                    if (act == 1)      v = (v >= 0.f) ? v : 0.1f * v;
                    else if (act == 2) v = 1.f / (1.f + __expf(-v));
                    else if (act == 3 && co >= 144) v = 1.f / (1.f + __expf(-v));
                    const int pix = r * WW + px0 + nt * 16 + pxl;
                    if (out_mode == 2)
                        ((unsigned short*)out)[((size_t)b * Cout + co) * HWC + pix] = bf16_rn(v);
                    else // c16
                        ((unsigned short*)out)[((size_t)(b * 4 + (co >> 4)) * HWC + pix) * 16 + (co & 15)] = bf16_rn(v);
                }
            }
        }
    }
}

// ---------------------------------------------------------------------------
// Fused dual modulated deformable conv (unchanged from R6 working version).
// ---------------------------------------------------------------------------
__global__ __launch_bounds__(256) void deform_fused_kernel(
    const unsigned int* __restrict__ xs,
    const unsigned short* __restrict__ om, const unsigned short* __restrict__ em,
    const float* __restrict__ wdc, const float* __restrict__ bdc,
    float* __restrict__ outx, float* __restrict__ outs)
{
    __shared__ __align__(16) unsigned int lds[24 * DROW * DPAD];   // 29952 B

    const int bg = blockIdx.x >> 6;           // b*8+g
    const int b = bg >> 3, g = bg & 7;
    const int tile = blockIdx.x & 63;
    const int r0 = (tile >> 3) << 4;
    const int c0 = (tile & 7) << 4;
    const int tx = threadIdx.x & 15, ty = threadIdx.x >> 4;
    const int h = r0 + ty, w = c0 + tx;
    const int wr0 = r0 - 4, wc0 = c0 - 4;

    const unsigned int* xsb = xs + ((size_t)b * 64 + g * 8) * HWC;

#pragma unroll
    for (int i = 0; i < 18; i++) {
        unsigned int slot = (unsigned int)threadIdx.x + i * 256u;   // 0..4607
        unsigned int sx = slot % 24u;
        unsigned int t2 = slot / 24u;
        unsigned int sy = t2 % 24u;
        unsigned int c  = t2 / 24u;
        int iy = min(max(wr0 + (int)sy, 0), HH - 1);
        int ix = min(max(wc0 + (int)sx, 0), WW - 1);
        lds[(sy * DROW + sx) * DPAD + c] = xsb[(size_t)c * HWC + iy * WW + ix];
    }

    __syncthreads();

    const int pix = h * WW + w;
    const unsigned short* omb = om + (size_t)b * 216 * HWC + pix + (size_t)g * 18 * HWC;
    const unsigned short* mmb = om + (size_t)b * 216 * HWC + pix + (size_t)(144 + g * 9) * HWC;
    const unsigned short* emb = em + (size_t)b * 72 * HWC + pix + (size_t)g * 9 * HWC;

    float accx[8], accs[8];
#pragma unroll
    for (int o = 0; o < 8; o++) { accx[o] = 0.f; accs[o] = 0.f; }

#pragma unroll
    for (int kk = 0; kk < 9; kk++) {
        const float dy = b2f(omb[(size_t)(kk * 2) * HWC]);
        const float dx = b2f(omb[(size_t)(kk * 2 + 1) * HWC]);
        const float m1 = b2f(mmb[(size_t)kk * HWC]);
        const float m2 = b2f(emb[(size_t)kk * HWC]);

        const float py = (float)(h - 1 + kk / 3) + dy;
        const float px = (float)(w - 1 + kk % 3) + dx;
        const float y0f = floorf(py), x0f = floorf(px);
        const float ly = py - y0f, lx = px - x0f;
        const int y0 = (int)y0f, x0 = (int)x0f;
        const int y1 = y0 + 1, x1 = x0 + 1;
        const bool vy0 = (y0 >= 0) && (y0 < HH), vy1 = (y1 >= 0) && (y1 < HH);
        const bool vx0 = (x0 >= 0) && (x0 < WW), vx1 = (x1 >= 0) && (x1 < WW);
        float w00 = (1.f - ly) * (1.f - lx); if (!(vy0 && vx0)) w00 = 0.f;
        float w01 = (1.f - ly) * lx;         if (!(vy0 && vx1)) w01 = 0.f;
        float w10 = ly * (1.f - lx);         if (!(vy1 && vx0)) w10 = 0.f;
        float w11 = ly * lx;                 if (!(vy1 && vx1)) w11 = 0.f;
        const int cy0 = min(max(y0, 0), HH - 1), cy1 = min(max(y1, 0), HH - 1);
        const int cx0 = min(max(x0, 0), WW - 1), cx1 = min(max(x1, 0), WW - 1);

        const int sy0 = cy0 - wr0, sy1 = cy1 - wr0;
        const int sx0 = cx0 - wc0, sx1 = cx1 - wc0;
        const bool inw = (sy0 >= 0) && (sy1 < 24) && (sx0 >= 0) && (sx1 < 24);

        const float* wk = wdc + (size_t)g * 8 * 8 * 9 + kk;   // wk[(o*8+c)*9]

        if (__builtin_expect(inw, 1)) {
            const int p00 = (sy0 * DROW + sx0) * DPAD, p01 = (sy0 * DROW + sx1) * DPAD;
            const int p10 = (sy1 * DROW + sx0) * DPAD, p11 = (sy1 * DROW + sx1) * DPAD;
#pragma unroll
            for (int ch = 0; ch < 2; ch++) {
                uint4 qa = *(const uint4*)(lds + p00 + ch * 4);
                uint4 qb = *(const uint4*)(lds + p01 + ch * 4);
                uint4 qc = *(const uint4*)(lds + p10 + ch * 4);
                uint4 qd = *(const uint4*)(lds + p11 + ch * 4);
                const unsigned int ua[4] = {qa.x, qa.y, qa.z, qa.w};
                const unsigned int ub[4] = {qb.x, qb.y, qb.z, qb.w};
                const unsigned int uc[4] = {qc.x, qc.y, qc.z, qc.w};
                const unsigned int ud[4] = {qd.x, qd.y, qd.z, qd.w};
#pragma unroll
                for (int j = 0; j < 4; j++) {
                    const int c = ch * 4 + j;
                    float x00 = __uint_as_float(ua[j] << 16), s00 = __uint_as_float(ua[j] & 0xffff0000u);
                    float x01 = __uint_as_float(ub[j] << 16), s01 = __uint_as_float(ub[j] & 0xffff0000u);
                    float x10 = __uint_as_float(uc[j] << 16), s10 = __uint_as_float(uc[j] & 0xffff0000u);
                    float x11 = __uint_as_float(ud[j] << 16), s11 = __uint_as_float(ud[j] & 0xffff0000u);
                    float vx = w00 * x00; vx = fmaf(w01, x01, vx); vx = fmaf(w10, x10, vx); vx = fmaf(w11, x11, vx);
                    float vs = w00 * s00; vs = fmaf(w01, s01, vs); vs = fmaf(w10, s10, vs); vs = fmaf(w11, s11, vs);
                    vx *= m1;
                    vs *= m2;
#pragma unroll
                    for (int o = 0; o < 8; o++) {
                        const float wv = wk[(size_t)(o * 8 + c) * 9];
                        accx[o] = fmaf(vx, wv, accx[o]);
                        accs[o] = fmaf(vs, wv, accs[o]);
                    }
                }
            }
        } else {
            const int i00 = cy0 * WW + cx0, i01 = cy0 * WW + cx1;
            const int i10 = cy1 * WW + cx0, i11 = cy1 * WW + cx1;
#pragma unroll
            for (int c = 0; c < 8; c++) {
                const unsigned int* xc = xsb + (size_t)c * HWC;
                unsigned int a = xc[i00], bq = xc[i01], cq = xc[i10], dq = xc[i11];
                float x00 = __uint_as_float(a << 16),  s00 = __uint_as_float(a & 0xffff0000u);
                float x01 = __uint_as_float(bq << 16), s01 = __uint_as_float(bq & 0xffff0000u);
                float x10 = __uint_as_float(cq << 16), s10 = __uint_as_float(cq & 0xffff0000u);
                float x11 = __uint_as_float(dq << 16), s11 = __uint_as_float(dq & 0xffff0000u);
                float vx = w00 * x00; vx = fmaf(w01, x01, vx); vx = fmaf(w10, x10, vx); vx = fmaf(w11, x11, vx);
                float vs = w00 * s00; vs = fmaf(w01, s01, vs); vs = fmaf(w10, s10, vs); vs = fmaf(w11, s11, vs);
                vx *= m1;
                vs *= m2;
#pragma unroll
                for (int o = 0; o < 8; o++) {
                    const float wv = wk[(size_t)(o * 8 + c) * 9];
                    accx[o] = fmaf(vx, wv, accx[o]);
                    accs[o] = fmaf(vs, wv, accs[o]);
                }
            }
        }
    }

#pragma unroll
    for (int o = 0; o < 8; o++) {
        const float bv = bdc[g * 8 + o];
        outx[((size_t)(b * COO + g * 8 + o)) * HWC + pix] = accx[o] + bv;
        outs[((size_t)(b * COO + g * 8 + o)) * HWC + pix] = accs[o] + bv;
    }
}

// ---------------------------------------------------------------------------
extern "C" void kernel_launch(void* const* d_in, const int* in_sizes, int n_in,
                              void* d_out, int out_size, void* d_ws, size_t ws_size,
                              hipStream_t stream) {
    const float* x      = (const float*)d_in[0];
    const float* share  = (const float*)d_in[1];
    const float* offf   = (const float*)d_in[2];
    const float* w_om   = (const float*)d_in[3];
    const float* b_om   = (const float*)d_in[4];
    const float* w_em1  = (const float*)d_in[5];
    const float* b_em1  = (const float*)d_in[6];
    const float* w_em2  = (const float*)d_in[7];
    const float* b_em2  = (const float*)d_in[8];
    const float* w_dc   = (const float*)d_in[9];
    const float* b_dc   = (const float*)d_in[10];

    // Workspace layout
    unsigned int* xs = (unsigned int*)d_ws;           // 4194304 u32
    unsigned short* us = (unsigned short*)(xs + 4194304);
    unsigned short* sc16   = us;                      // 4194304 ush (share c16)
    unsigned short* oc16   = sc16 + 4194304;          // 4194304 (offf c16)
    unsigned short* emm    = oc16 + 4194304;          // 4194304 (em_mid c16)
    unsigned short* om_b   = emm + 4194304;           // 14155776 (om NCHW bf16)
    unsigned short* em_b   = om_b + 14155776;         // 4718592 (em NCHW bf16)
    unsigned short* wp_om  = em_b + 4718592;          // 147456 (COP=256)
    unsigned short* wp_em1 = wp_om + 147456;          // 73728  (COP=64)
    unsigned short* wp_em2 = wp_em1 + 73728;          // 73728  (COP=128)

    float* outx = (float*)d_out;
    float* outs = outx + 4194304;

    dim3 blk(256);

    // Fused input + weight packing (2 launches)
    pack_inputs_kernel<<<dim3(HWC / 64, BB), blk, 0, stream>>>(x, share, offf, xs, sc16, oc16);
    pack_w_all_kernel<<<(147456 + 73728 + 73728) / 256, blk, 0, stream>>>(
        w_om, wp_om, w_em1, wp_em1, w_em2, wp_em2);

    // om = conv(offset_feat) 64->216, sigmoid on mask channels, NCHW bf16
    conv_mfma_kernel<1, 256><<<dim3(256, 4), blk, 0, stream>>>(
        oc16, nullptr, wp_om, b_om, om_b, 216, 2, 3);
    // em_mid = leaky(conv(concat(share, offf))) 128->64, c16 bf16
    conv_mfma_kernel<2, 64><<<dim3(256, 1), blk, 0, stream>>>(
        sc16, oc16, wp_em1, b_em1, emm, 64, 3, 1);
    // em = sigmoid(conv(em_mid)) 64->72, NCHW bf16
    conv_mfma_kernel<1, 128><<<dim3(256, 2), blk, 0, stream>>>(
        emm, nullptr, wp_em2, b_em2, em_b, 72, 2, 2);

    // fused dual deformable conv (LDS-staged gathers)
    deform_fused_kernel<<<dim3(BB * GG * 64), blk, 0, stream>>>(
        xs, om_b, em_b, w_dc, b_dc, outx, outs);
}

// Round 4
// 284.432 us; speedup vs baseline: 1.7675x; 1.7675x over previous
//
#include <hip/hip_runtime.h>
#include <math.h>

// Problem constants
#define BB 4
#define CC 64
#define HH 128
#define WW 128
#define GG 8
#define COO 64
#define HWC (HH*WW)

// Deform LDS layout: pixel stride 12 u32 (48 B, 16B aligned), row padded to 26
#define DPAD 12
#define DROW 26

typedef float f32x4 __attribute__((ext_vector_type(4)));
typedef __bf16 bf16x8 __attribute__((ext_vector_type(8)));

__device__ __forceinline__ unsigned short bf16_rn(float f) {
    unsigned int u = __float_as_uint(f);
    unsigned int r = (u + 0x7fffu + ((u >> 16) & 1u)) >> 16;
    return (unsigned short)r;
}
__device__ __forceinline__ float b2f(unsigned short u) {
    return __uint_as_float(((unsigned int)u) << 16);
}

// ---------------------------------------------------------------------------
// Fused input pack: one launch produces
//   xs   : NCHW u32 {lo=bf16(x), hi=bf16(share)}   (deform source)
//   sc16 : share in c16 layout [((b*4+cg)*HWC+pix)*16+ci]  (conv B)
//   oc16 : offset_feat in c16 layout                       (conv B)
// ---------------------------------------------------------------------------
__global__ __launch_bounds__(256) void pack_inputs_kernel(
    const float* __restrict__ x, const float* __restrict__ share,
    const float* __restrict__ offf,
    unsigned int* __restrict__ xs, unsigned short* __restrict__ sc16,
    unsigned short* __restrict__ oc16)
{
    __shared__ unsigned short lds[64][66];
    const int b = blockIdx.y;
    const int pix0 = blockIdx.x * 64;
    const int t = threadIdx.x;
    const int p = t & 63, q = t >> 6;
    const int pl = t & 63, cg = t >> 6;

    // Phase 1: share -> lds + xs write (share & x elementwise)
#pragma unroll
    for (int i = 0; i < 16; i++) {
        int c = i * 4 + q;
        size_t idx = ((size_t)b * 64 + c) * HWC + pix0 + p;
        unsigned short sb = bf16_rn(share[idx]);
        lds[c][p] = sb;
        xs[idx] = (unsigned int)bf16_rn(x[idx]) | ((unsigned int)sb << 16);
    }
    __syncthreads();
    {
        unsigned int u[8];
#pragma unroll
        for (int j = 0; j < 8; j++) {
            unsigned int lo = lds[cg * 16 + 2 * j][pl];
            unsigned int hi = lds[cg * 16 + 2 * j + 1][pl];
            u[j] = lo | (hi << 16);
        }
        unsigned int* dst = (unsigned int*)(sc16 + ((size_t)(b * 4 + cg) * HWC + pix0 + pl) * 16);
        *(uint4*)dst = make_uint4(u[0], u[1], u[2], u[3]);
        *(uint4*)(dst + 4) = make_uint4(u[4], u[5], u[6], u[7]);
    }
    __syncthreads();

    // Phase 2: offset_feat -> lds -> oc16
#pragma unroll
    for (int i = 0; i < 16; i++) {
        int c = i * 4 + q;
        lds[c][p] = bf16_rn(offf[((size_t)b * 64 + c) * HWC + pix0 + p]);
    }
    __syncthreads();
    {
        unsigned int u[8];
#pragma unroll
        for (int j = 0; j < 8; j++) {
            unsigned int lo = lds[cg * 16 + 2 * j][pl];
            unsigned int hi = lds[cg * 16 + 2 * j + 1][pl];
            u[j] = lo | (hi << 16);
        }
        unsigned int* dst = (unsigned int*)(oc16 + ((size_t)(b * 4 + cg) * HWC + pix0 + pl) * 16);
        *(uint4*)dst = make_uint4(u[0], u[1], u[2], u[3]);
        *(uint4*)(dst + 4) = make_uint4(u[4], u[5], u[6], u[7]);
    }
}

// ---------------------------------------------------------------------------
// Weight packs for 16x16x32 MFMA fragments.
// Layout: wp[(t*(COP/16)+cob)*64 + lane][8] bf16, where t = seg*18 + kk*2 + ks,
// lane holds co = cob*16+(lane&15), k_local = (lane>>4)*8 + j (j=0..7),
// cg = 2*ks + (k_local>>4), ci = k_local&15, cin = seg*64 + cg*16 + ci.
// Sizes: om 18*256*32=147456, em1 36*64*32=73728, em2 18*128*32=73728.
// ---------------------------------------------------------------------------
__device__ __forceinline__ void pack_w_one(const float* __restrict__ w,
                                           unsigned short* __restrict__ wp,
                                           int Cout, int COP, int CinTot, int idx) {
    int j    = idx & 7;
    int lane = (idx >> 3) & 63;
    int rem  = idx >> 9;              // t*(COP/16) + cob
    int ncob = COP >> 4;
    int cob  = rem % ncob;
    int t    = rem / ncob;
    int seg  = t / 18;
    int tt   = t % 18;
    int kk   = tt >> 1;
    int ks   = tt & 1;
    int co   = cob * 16 + (lane & 15);
    int kl   = ((lane >> 4) << 3) + j;     // 0..31
    int cg   = ks * 2 + (kl >> 4);
    int ci   = kl & 15;
    int cin  = seg * 64 + cg * 16 + ci;
    float v = (co < Cout) ? w[((size_t)co * CinTot + cin) * 9 + kk] : 0.f;
    wp[idx] = bf16_rn(v);
}

__global__ void pack_w_all_kernel(const float* __restrict__ w_om, unsigned short* __restrict__ wp_om,
                                  const float* __restrict__ w_em1, unsigned short* __restrict__ wp_em1,
                                  const float* __restrict__ w_em2, unsigned short* __restrict__ wp_em2) {
    int i = blockIdx.x * 256 + threadIdx.x;
    if (i < 147456) {
        pack_w_one(w_om, wp_om, 216, 256, 64, i);
    } else if (i < 147456 + 73728) {
        pack_w_one(w_em1, wp_em1, 64, 64, 128, i - 147456);
    } else if (i < 147456 + 73728 + 73728) {
        pack_w_one(w_em2, wp_em2, 72, 128, 64, i - 147456 - 73728);
    }
}

// ---------------------------------------------------------------------------
// Implicit-GEMM 3x3 conv via mfma_f32_16x16x32_bf16, inputs in c16 layout.
//
// R10: give the register allocator LICENSE. R9 post-mortem: VGPR stopped at
// 100 = acc(64) + ONE af + ONE bf + addressing -> compiler serialized the
// step into ~5 load-wait-MFMA chains (MfmaUtil 5.8%). The occupancy-driven
// VGPR cap is what has sunk every pipelining attempt (R8 rotation collapsed,
// R9 frags serialized). __launch_bounds__(256, 2) declares 2 waves/EU ->
// ~256 VGPR budget -> all 8 frags stay live and the list scheduler hoists
// loads across MFMAs on its own. LDS (50688 B, 3 blocks/CU) caps occupancy
// anyway, so the declared-occupancy loss is free.
// NCOB = co-blocks-of-16 per wave (em1 restored to 32-co tiles, grid.y=2;
// R9's grid.y=1 was 1 block/CU).
// ---------------------------------------------------------------------------
template<int NSEG, int COP, int NCOB>
__global__ __launch_bounds__(256, 2) void conv_mfma_kernel(
    const unsigned short* __restrict__ in0,
    const unsigned short* __restrict__ in1,
    const unsigned short* __restrict__ wp,
    const float* __restrict__ bias,
    void* __restrict__ out,
    int Cout, int out_mode, int act)
{
    constexpr int PXW = 66;            // 64 px + 1 halo each side
    constexpr int NE  = 4 * 6 * PXW;   // 1584 entries of 32 B (16 bf16 ch)
    __shared__ __align__(16) unsigned short slds[NE * 16];   // 50688 B

    const int lane = threadIdx.x & 63;
    const int wid  = threadIdx.x >> 6;
    int tmp = blockIdx.x;
    const int xsp = tmp & 1; tmp >>= 1;    // XS = 2
    const int rb  = tmp & 31;              // HH/4 = 32
    const int b   = tmp >> 5;
    const int r0  = rb * 4;
    const int r   = r0 + wid;              // output row, wave-uniform
    const int px0 = xsp * 64;
    const int cb0 = blockIdx.y * NCOB;     // co block-of-16 base
    const int co0 = blockIdx.y * (16 * NCOB);

    f32x4 acc[NCOB][4];
#pragma unroll
    for (int cob = 0; cob < NCOB; cob++)
#pragma unroll
        for (int nt = 0; nt < 4; nt++)
#pragma unroll
            for (int rg = 0; rg < 4; rg++) acc[cob][nt][rg] = 0.f;

    // B-fragment lane mapping for 16x16x32: col(px)=lane&15, k=(lane>>4)*8+j.
    // k 0..31 -> lane groups {cg0 ci0-7, cg0 ci8-15, cg1 ci0-7, cg1 ci8-15}.
    const int pxl  = lane & 15;
    const int kgrp = lane >> 4;            // 0..3
    const int cglh = lane >> 5;            // cg within pair
    const int cil0 = (kgrp & 1) * 8;       // ci half
    const unsigned short* lp = slds +
        ((size_t)(cglh * 6 + wid) * PXW + 1 + pxl) * 16 + cil0;

#pragma unroll
    for (int seg = 0; seg < NSEG; seg++) {
        const unsigned short* inb = (seg ? in1 : in0) + (size_t)b * 4 * HWC * 16;
        if (seg) __syncthreads();

        // ---- Stage 4 cg x 6 rows x 66 px, zero-padded (conv zero-padding) ----
#pragma unroll
        for (int i = 0; i < 7; i++) {
            const int e = (int)threadIdx.x + i * 256;
            if (i < 6 || e < NE) {
                const int cg  = e / (6 * PXW);
                const int rem = e - cg * (6 * PXW);
                const int row = rem / PXW;
                const int px  = rem - row * PXW;
                const int iy = r0 - 1 + row;
                const int ix = px0 - 1 + px;
                const bool valid = ((unsigned)iy < (unsigned)HH) && ((unsigned)ix < (unsigned)WW);
                const int iyc = min(max(iy, 0), HH - 1);
                const int ixc = min(max(ix, 0), WW - 1);
                const uint4* src = (const uint4*)(inb + ((size_t)cg * HWC + (size_t)iyc * WW + ixc) * 16);
                uint4 v0, v1;
                if (valid) { v0 = src[0]; v1 = src[1]; }
                else       { v0 = make_uint4(0u, 0u, 0u, 0u); v1 = v0; }
                uint4* dst = (uint4*)(slds + (size_t)e * 16);
                dst[0] = v0; dst[1] = v1;
            }
        }
        __syncthreads();

        // ---- Straight-line K loop: 18 steps of K=32, all offsets immediate ----
#pragma unroll
        for (int kk = 0; kk < 9; kk++) {
            const int kh = kk / 3, kw = kk % 3;
#pragma unroll
            for (int ks = 0; ks < 2; ks++) {
                const int t = seg * 18 + kk * 2 + ks;
                bf16x8 af[NCOB];
#pragma unroll
                for (int cob = 0; cob < NCOB; cob++)
                    af[cob] = *(const bf16x8*)(wp +
                        ((size_t)(t * (COP >> 4) + cb0 + cob) * 64 + lane) * 8);
                bf16x8 bf[4];
#pragma unroll
                for (int nt = 0; nt < 4; nt++)
                    bf[nt] = *(const bf16x8*)(lp +
                        ((ks * 12 + kh) * PXW + nt * 16 + kw - 1) * 16);
#pragma unroll
                for (int cob = 0; cob < NCOB; cob++)
#pragma unroll
                    for (int nt = 0; nt < 4; nt++)
                        acc[cob][nt] = __builtin_amdgcn_mfma_f32_16x16x32_bf16(
                            af[cob], bf[nt], acc[cob][nt], 0, 0, 0);
            }
        }
    }

    // Epilogue: 16x16 D layout col(px)=lane&15, row(co)=(lane>>4)*4+rg
#pragma unroll
    for (int cob = 0; cob < NCOB; cob++) {
#pragma unroll
        for (int nt = 0; nt < 4; nt++) {
#pragma unroll
            for (int rg = 0; rg < 4; rg++) {
                const int co = co0 + cob * 16 + kgrp * 4 + rg;
                if (co < Cout) {
                    float v = acc[cob][nt][rg] + bias[co];
                    if (act == 1)      v = (v >= 0.f) ? v : 0.1f * v;
                    else if (act == 2) v = 1.f / (1.f + __expf(-v));
                    else if (act == 3 && co >= 144) v = 1.f / (1.f + __expf(-v));
                    const int pix = r * WW + px0 + nt * 16 + pxl;
                    if (out_mode == 2)
                        ((unsigned short*)out)[((size_t)b * Cout + co) * HWC + pix] = bf16_rn(v);
                    else // c16
                        ((unsigned short*)out)[((size_t)(b * 4 + (co >> 4)) * HWC + pix) * 16 + (co & 15)] = bf16_rn(v);
                }
            }
        }
    }
}

// ---------------------------------------------------------------------------
// Fused dual modulated deformable conv (unchanged from R6 working version).
// ---------------------------------------------------------------------------
__global__ __launch_bounds__(256) void deform_fused_kernel(
    const unsigned int* __restrict__ xs,
    const unsigned short* __restrict__ om, const unsigned short* __restrict__ em,
    const float* __restrict__ wdc, const float* __restrict__ bdc,
    float* __restrict__ outx, float* __restrict__ outs)
{
    __shared__ __align__(16) unsigned int lds[24 * DROW * DPAD];   // 29952 B

    const int bg = blockIdx.x >> 6;           // b*8+g
    const int b = bg >> 3, g = bg & 7;
    const int tile = blockIdx.x & 63;
    const int r0 = (tile >> 3) << 4;
    const int c0 = (tile & 7) << 4;
    const int tx = threadIdx.x & 15, ty = threadIdx.x >> 4;
    const int h = r0 + ty, w = c0 + tx;
    const int wr0 = r0 - 4, wc0 = c0 - 4;

    const unsigned int* xsb = xs + ((size_t)b * 64 + g * 8) * HWC;

#pragma unroll
    for (int i = 0; i < 18; i++) {
        unsigned int slot = (unsigned int)threadIdx.x + i * 256u;   // 0..4607
        unsigned int sx = slot % 24u;
        unsigned int t2 = slot / 24u;
        unsigned int sy = t2 % 24u;
        unsigned int c  = t2 / 24u;
        int iy = min(max(wr0 + (int)sy, 0), HH - 1);
        int ix = min(max(wc0 + (int)sx, 0), WW - 1);
        lds[(sy * DROW + sx) * DPAD + c] = xsb[(size_t)c * HWC + iy * WW + ix];
    }

    __syncthreads();

    const int pix = h * WW + w;
    const unsigned short* omb = om + (size_t)b * 216 * HWC + pix + (size_t)g * 18 * HWC;
    const unsigned short* mmb = om + (size_t)b * 216 * HWC + pix + (size_t)(144 + g * 9) * HWC;
    const unsigned short* emb = em + (size_t)b * 72 * HWC + pix + (size_t)g * 9 * HWC;

    float accx[8], accs[8];
#pragma unroll
    for (int o = 0; o < 8; o++) { accx[o] = 0.f; accs[o] = 0.f; }

#pragma unroll
    for (int kk = 0; kk < 9; kk++) {
        const float dy = b2f(omb[(size_t)(kk * 2) * HWC]);
        const float dx = b2f(omb[(size_t)(kk * 2 + 1) * HWC]);
        const float m1 = b2f(mmb[(size_t)kk * HWC]);
        const float m2 = b2f(emb[(size_t)kk * HWC]);

        const float py = (float)(h - 1 + kk / 3) + dy;
        const float px = (float)(w - 1 + kk % 3) + dx;
        const float y0f = floorf(py), x0f = floorf(px);
        const float ly = py - y0f, lx = px - x0f;
        const int y0 = (int)y0f, x0 = (int)x0f;
        const int y1 = y0 + 1, x1 = x0 + 1;
        const bool vy0 = (y0 >= 0) && (y0 < HH), vy1 = (y1 >= 0) && (y1 < HH);
        const bool vx0 = (x0 >= 0) && (x0 < WW), vx1 = (x1 >= 0) && (x1 < WW);
        float w00 = (1.f - ly) * (1.f - lx); if (!(vy0 && vx0)) w00 = 0.f;
        float w01 = (1.f - ly) * lx;         if (!(vy0 && vx1)) w01 = 0.f;
        float w10 = ly * (1.f - lx);         if (!(vy1 && vx0)) w10 = 0.f;
        float w11 = ly * lx;                 if (!(vy1 && vx1)) w11 = 0.f;
        const int cy0 = min(max(y0, 0), HH - 1), cy1 = min(max(y1, 0), HH - 1);
        const int cx0 = min(max(x0, 0), WW - 1), cx1 = min(max(x1, 0), WW - 1);

        const int sy0 = cy0 - wr0, sy1 = cy1 - wr0;
        const int sx0 = cx0 - wc0, sx1 = cx1 - wc0;
        const bool inw = (sy0 >= 0) && (sy1 < 24) && (sx0 >= 0) && (sx1 < 24);

        const float* wk = wdc + (size_t)g * 8 * 8 * 9 + kk;   // wk[(o*8+c)*9]

        if (__builtin_expect(inw, 1)) {
            const int p00 = (sy0 * DROW + sx0) * DPAD, p01 = (sy0 * DROW + sx1) * DPAD;
            const int p10 = (sy1 * DROW + sx0) * DPAD, p11 = (sy1 * DROW + sx1) * DPAD;
#pragma unroll
            for (int ch = 0; ch < 2; ch++) {
                uint4 qa = *(const uint4*)(lds + p00 + ch * 4);
                uint4 qb = *(const uint4*)(lds + p01 + ch * 4);
                uint4 qc = *(const uint4*)(lds + p10 + ch * 4);
                uint4 qd = *(const uint4*)(lds + p11 + ch * 4);
                const unsigned int ua[4] = {qa.x, qa.y, qa.z, qa.w};
                const unsigned int ub[4] = {qb.x, qb.y, qb.z, qb.w};
                const unsigned int uc[4] = {qc.x, qc.y, qc.z, qc.w};
                const unsigned int ud[4] = {qd.x, qd.y, qd.z, qd.w};
#pragma unroll
                for (int j = 0; j < 4; j++) {
                    const int c = ch * 4 + j;
                    float x00 = __uint_as_float(ua[j] << 16), s00 = __uint_as_float(ua[j] & 0xffff0000u);
                    float x01 = __uint_as_float(ub[j] << 16), s01 = __uint_as_float(ub[j] & 0xffff0000u);
                    float x10 = __uint_as_float(uc[j] << 16), s10 = __uint_as_float(uc[j] & 0xffff0000u);
                    float x11 = __uint_as_float(ud[j] << 16), s11 = __uint_as_float(ud[j] & 0xffff0000u);
                    float vx = w00 * x00; vx = fmaf(w01, x01, vx); vx = fmaf(w10, x10, vx); vx = fmaf(w11, x11, vx);
                    float vs = w00 * s00; vs = fmaf(w01, s01, vs); vs = fmaf(w10, s10, vs); vs = fmaf(w11, s11, vs);
                    vx *= m1;
                    vs *= m2;
#pragma unroll
                    for (int o = 0; o < 8; o++) {
                        const float wv = wk[(size_t)(o * 8 + c) * 9];
                        accx[o] = fmaf(vx, wv, accx[o]);
                        accs[o] = fmaf(vs, wv, accs[o]);
                    }
                }
            }
        } else {
            const int i00 = cy0 * WW + cx0, i01 = cy0 * WW + cx1;
            const int i10 = cy1 * WW + cx0, i11 = cy1 * WW + cx1;
#pragma unroll
            for (int c = 0; c < 8; c++) {
                const unsigned int* xc = xsb + (size_t)c * HWC;
                unsigned int a = xc[i00], bq = xc[i01], cq = xc[i10], dq = xc[i11];
                float x00 = __uint_as_float(a << 16),  s00 = __uint_as_float(a & 0xffff0000u);
                float x01 = __uint_as_float(bq << 16), s01 = __uint_as_float(bq & 0xffff0000u);
                float x10 = __uint_as_float(cq << 16), s10 = __uint_as_float(cq & 0xffff0000u);
                float x11 = __uint_as_float(dq << 16), s11 = __uint_as_float(dq & 0xffff0000u);
                float vx = w00 * x00; vx = fmaf(w01, x01, vx); vx = fmaf(w10, x10, vx); vx = fmaf(w11, x11, vx);
                float vs = w00 * s00; vs = fmaf(w01, s01, vs); vs = fmaf(w10, s10, vs); vs = fmaf(w11, s11, vs);
                vx *= m1;
                vs *= m2;
#pragma unroll
                for (int o = 0; o < 8; o++) {
                    const float wv = wk[(size_t)(o * 8 + c) * 9];
                    accx[o] = fmaf(vx, wv, accx[o]);
                    accs[o] = fmaf(vs, wv, accs[o]);
                }
            }
        }
    }

#pragma unroll
    for (int o = 0; o < 8; o++) {
        const float bv = bdc[g * 8 + o];
        outx[((size_t)(b * COO + g * 8 + o)) * HWC + pix] = accx[o] + bv;
        outs[((size_t)(b * COO + g * 8 + o)) * HWC + pix] = accs[o] + bv;
    }
}

// ---------------------------------------------------------------------------
extern "C" void kernel_launch(void* const* d_in, const int* in_sizes, int n_in,
                              void* d_out, int out_size, void* d_ws, size_t ws_size,
                              hipStream_t stream) {
    const float* x      = (const float*)d_in[0];
    const float* share  = (const float*)d_in[1];
    const float* offf   = (const float*)d_in[2];
    const float* w_om   = (const float*)d_in[3];
    const float* b_om   = (const float*)d_in[4];
    const float* w_em1  = (const float*)d_in[5];
    const float* b_em1  = (const float*)d_in[6];
    const float* w_em2  = (const float*)d_in[7];
    const float* b_em2  = (const float*)d_in[8];
    const float* w_dc   = (const float*)d_in[9];
    const float* b_dc   = (const float*)d_in[10];

    // Workspace layout
    unsigned int* xs = (unsigned int*)d_ws;           // 4194304 u32
    unsigned short* us = (unsigned short*)(xs + 4194304);
    unsigned short* sc16   = us;                      // 4194304 ush (share c16)
    unsigned short* oc16   = sc16 + 4194304;          // 4194304 (offf c16)
    unsigned short* emm    = oc16 + 4194304;          // 4194304 (em_mid c16)
    unsigned short* om_b   = emm + 4194304;           // 14155776 (om NCHW bf16)
    unsigned short* em_b   = om_b + 14155776;         // 4718592 (em NCHW bf16)
    unsigned short* wp_om  = em_b + 4718592;          // 147456 (COP=256)
    unsigned short* wp_em1 = wp_om + 147456;          // 73728  (COP=64)
    unsigned short* wp_em2 = wp_em1 + 73728;          // 73728  (COP=128)

    float* outx = (float*)d_out;
    float* outs = outx + 4194304;

    dim3 blk(256);

    // Fused input + weight packing (2 launches)
    pack_inputs_kernel<<<dim3(HWC / 64, BB), blk, 0, stream>>>(x, share, offf, xs, sc16, oc16);
    pack_w_all_kernel<<<(147456 + 73728 + 73728) / 256, blk, 0, stream>>>(
        w_om, wp_om, w_em1, wp_em1, w_em2, wp_em2);

    // om = conv(offset_feat) 64->216, sigmoid on mask channels, NCHW bf16
    conv_mfma_kernel<1, 256, 4><<<dim3(256, 4), blk, 0, stream>>>(
        oc16, nullptr, wp_om, b_om, om_b, 216, 2, 3);
    // em_mid = leaky(conv(concat(share, offf))) 128->64, c16 bf16 (32-co tiles)
    conv_mfma_kernel<2, 64, 2><<<dim3(256, 2), blk, 0, stream>>>(
        sc16, oc16, wp_em1, b_em1, emm, 64, 3, 1);
    // em = sigmoid(conv(em_mid)) 64->72, NCHW bf16
    conv_mfma_kernel<1, 128, 4><<<dim3(256, 2), blk, 0, stream>>>(
        emm, nullptr, wp_em2, b_em2, em_b, 72, 2, 2);

    // fused dual deformable conv (LDS-staged gathers)
    deform_fused_kernel<<<dim3(BB * GG * 64), blk, 0, stream>>>(
        xs, om_b, em_b, w_dc, b_dc, outx, outs);
}